// Round 5
// baseline (781.733 us; speedup 1.0000x reference)
//
#include <hip/hip_runtime.h>
#include <hip/hip_bf16.h>
#include <stdint.h>

// Problem constants
#define S_LEN 1024
#define B_SZ  64
#define I_SZ  512
#define H_SZ  2048
#define O_SZ  512

typedef __bf16  bf16x8 __attribute__((ext_vector_type(8)));
typedef float   f32x4  __attribute__((ext_vector_type(4)));

static __device__ __forceinline__ ushort f2bf(float f) {
  union { float f; unsigned u; } v; v.f = f;
  unsigned r = v.u + 0x7FFFu + ((v.u >> 16) & 1u);   // RNE
  return (ushort)(r >> 16);
}
static __device__ __forceinline__ float bf2f(ushort u) {
  return __builtin_bit_cast(float, (unsigned)u << 16);
}

// async global->LDS, 16B per lane (prologue only)
#define GLOAD_LDS16(gp, lp) \
  __builtin_amdgcn_global_load_lds( \
      (__attribute__((address_space(1))) void*)(gp), \
      (__attribute__((address_space(3))) void*)(lp), 16, 0, 0)

// ---------------------------------------------------------------- W convert (tiny)
__global__ __launch_bounds__(256) void convert_f32_bf16_kernel(
    const float4* __restrict__ in, ushort4* __restrict__ out, int n4) {
  int i = blockIdx.x * 256 + threadIdx.x;
  if (i >= n4) return;
  float4 v = in[i];
  ushort4 o; o.x = f2bf(v.x); o.y = f2bf(v.y); o.z = f2bf(v.z); o.w = f2bf(v.w);
  out[i] = o;
}

// ---------------------------------------------------------------- X convert+transpose
// X[s][b][i] fp32 -> Xbf[b][s][i] bf16. One wave per (s,b) row.
__global__ __launch_bounds__(256) void convert_x_kernel(
    const float* __restrict__ X, ushort* __restrict__ Xt) {
  const int row  = blockIdx.x * 4 + (threadIdx.x >> 6);  // s*64 + b
  const int lane = threadIdx.x & 63;
  const int s = row >> 6, b = row & 63;
  const float* src = X + (size_t)row * I_SZ + lane * 8;
  float4 v0 = *(const float4*)src;
  float4 v1 = *(const float4*)(src + 4);
  union { ushort h[8]; uint4 v; } o;
  o.h[0] = f2bf(v0.x); o.h[1] = f2bf(v0.y); o.h[2] = f2bf(v0.z); o.h[3] = f2bf(v0.w);
  o.h[4] = f2bf(v1.x); o.h[5] = f2bf(v1.y); o.h[6] = f2bf(v1.z); o.h[7] = f2bf(v1.w);
  *(uint4*)(Xt + ((size_t)b * S_LEN + s) * I_SZ + lane * 8) = o.v;
}

// ---------------------------------------------------------------- Y = bias (runs BEFORE fused)
__global__ __launch_bounds__(256) void init_y_kernel(
    const float* __restrict__ bho, float* __restrict__ Y) {
  int idx = blockIdx.x * 256 + threadIdx.x;   // 0..32767
  Y[idx] = bho[idx & (O_SZ - 1)];
}

#define SCAN16(colp, s0_) do { \
    ushort4 v0 = *(const ushort4*)&(colp)[(s0_)]; \
    ushort4 v1 = *(const ushort4*)&(colp)[(s0_) + 4]; \
    ushort4 v2 = *(const ushort4*)&(colp)[(s0_) + 8]; \
    ushort4 v3 = *(const ushort4*)&(colp)[(s0_) + 12]; \
    p = fmaf(c, fabsf(p), bf2f(v0.x)); p = fmaf(c, fabsf(p), bf2f(v0.y)); \
    p = fmaf(c, fabsf(p), bf2f(v0.z)); p = fmaf(c, fabsf(p), bf2f(v0.w)); \
    p = fmaf(c, fabsf(p), bf2f(v1.x)); p = fmaf(c, fabsf(p), bf2f(v1.y)); \
    p = fmaf(c, fabsf(p), bf2f(v1.z)); p = fmaf(c, fabsf(p), bf2f(v1.w)); \
    p = fmaf(c, fabsf(p), bf2f(v2.x)); p = fmaf(c, fabsf(p), bf2f(v2.y)); \
    p = fmaf(c, fabsf(p), bf2f(v2.z)); p = fmaf(c, fabsf(p), bf2f(v2.w)); \
    p = fmaf(c, fabsf(p), bf2f(v3.x)); p = fmaf(c, fabsf(p), bf2f(v3.y)); \
    p = fmaf(c, fabsf(p), bf2f(v3.z)); p = fmaf(c, fabsf(p), bf2f(v3.w)); \
  } while (0)

// ---------------------------------------------------------------- fused GEMM + scan + projection
// Grid: 1024 blocks = (b, ht). R3 skeleton (same LDS image, same frag reads,
// same epilogue/scan/tail) with T14 register-staged async-split staging:
//   body t: [issue 8 global_load_dwordx4 -> regs (tile t+1)]   <- early issue
//           [ds_read frags + 32 MFMA (tile t)]                 <- covers latency
//           __syncthreads()   <- vmcnt(0) drain happens AFTER compute cover
//           [ds_write regs -> As/Bs (tile t+1)]
//           __syncthreads()   <- only ~50cy ds_write exposed
// This fixes the R0/R3 invariant limiter: their sync came IMMEDIATELY after
// staging-issue, exposing full L2/HBM latency every K-step. Cs overlays
// As/Bs (LDS 33792 B -> 4 blocks/CU at launch_bounds(256,4)); at kt==7 the
// epilogue+scan run between the two syncs, before the ds_write.
__global__ __launch_bounds__(256, 4) void fused_gemm_scan_kernel(
    const ushort* __restrict__ Xbf,   // [64][1024][512] bf16, batch-major
    const ushort* __restrict__ Wbf,   // [2048][512] bf16
    const float* __restrict__ hh,     // [2048]
    const float* __restrict__ Who,    // [512][2048] fp32
    float* __restrict__ Y) {          // [64][512], pre-seeded with bias
  __shared__ __align__(16) ushort smem[16896];   // 33792 B
  ushort* As = smem;                  // [128][64], rotate-swizzled
  ushort* Bs = smem + 8192;           // [128][64], rotate-swizzled
  ushort* Cs = smem;                  // [128 h][132 s] overlay

  const int tid  = threadIdx.x;
  const int wave = tid >> 6;
  const int lane = tid & 63;

  const int bid = blockIdx.x;
  const int xcd = bid & 7;            // XCD (bid%8 heuristic)
  const int g   = bid >> 3;           // 0..127
  const int b   = (xcd << 3) | (g & 7);  // same-b -> same XCD (Xbf L2 reuse)
  const int ht  = g >> 3;             // h-tile 0..15

  const int wm = (wave >> 1) * 64;    // s-offset within tile
  const int wn = (wave & 1) * 64;     // h-offset within tile
  const int ml = lane & 15;
  const int q  = lane >> 4;

  // ---- staging pattern (A and B identical): wave stages 32 rows of 64 bf16;
  //      slot s of LDS row r holds global chunk (s - r)&7 (rotate).
  const int r0     = wave * 32;
  const int srow   = lane >> 3;
  const int schunk = ((lane & 7) - srow) & 7;
  const ushort* gA = Xbf + (size_t)b * (S_LEN * I_SZ)
                   + (size_t)(r0 + srow) * I_SZ + schunk * 8;
  const ushort* gB = Wbf + (size_t)(ht * 128 + r0 + srow) * I_SZ + schunk * 8;
  // LDS write targets: row r0+srow+jj*8, slot lane&7 (matches rotate image)
  ushort* lA = As + (r0 + srow) * 64 + (lane & 7) * 8;
  ushort* lB = Bs + (r0 + srow) * 64 + (lane & 7) * 8;
  // prologue gload_lds targets (linear lane*16 within wave's 32-row span)
  ushort* pA = As + r0 * 64;
  ushort* pB = Bs + r0 * 64;

  // fragment offsets: chunk ks*4+q of row r lives at slot (ks*4+q + r)&7
  int foff[2];
  foff[0] = ((q + ml) & 7) * 8;
  foff[1] = ((4 + q + ml) & 7) * 8;
  int arow[4], brow[4];
  #pragma unroll
  for (int i = 0; i < 4; ++i) {
    arow[i] = (wm + i * 16 + ml) * 64;
    brow[i] = (wn + i * 16 + ml) * 64;
  }

  float c = 0.0f, p = 0.0f;           // scan state (p: pre-abs h)
  if (tid < 128) c = hh[ht * 128 + tid];

  // ---------------- prologue: stage tile 0 via global_load_lds
  #pragma unroll
  for (int jj = 0; jj < 4; ++jj) {
    GLOAD_LDS16(gA + (size_t)(jj * 8) * I_SZ, pA + jj * 512);
    GLOAD_LDS16(gB + (size_t)(jj * 8) * I_SZ, pB + jj * 512);
  }
  __syncthreads();                    // tile 0 visible (one exposed drain)

  f32x4 acc[4][4];

  #pragma unroll 1
  for (int t = 0; t < 64; ++t) {      // t = st*8 + kt
    const int kt = t & 7;
    if (kt == 0) {
      #pragma unroll
      for (int mi = 0; mi < 4; ++mi)
        #pragma unroll
        for (int ni = 0; ni < 4; ++ni) {
          f32x4 z = {0.f, 0.f, 0.f, 0.f};
          acc[mi][ni] = z;
        }
    }

    // ---- issue staging loads for tile t+1 into registers (early issue)
    uint4 rA[4], rB[4];
    if (t < 63) {
      const int n1 = t + 1;
      const ushort* ga = gA + (size_t)(n1 >> 3) * (128 * I_SZ) + (n1 & 7) * 64;
      const ushort* gb = gB + (size_t)(n1 & 7) * 64;
      #pragma unroll
      for (int jj = 0; jj < 4; ++jj) {
        rA[jj] = *(const uint4*)(ga + (size_t)(jj * 8) * I_SZ);
        rB[jj] = *(const uint4*)(gb + (size_t)(jj * 8) * I_SZ);
      }
    }

    // ---- compute tile t from LDS (compiler-scheduled ds_read/MFMA)
    #pragma unroll
    for (int ks = 0; ks < 2; ++ks) {
      bf16x8 af[4], bfr[4];
      #pragma unroll
      for (int i = 0; i < 4; ++i) {
        af[i]  = *(const bf16x8*)&As[arow[i] + foff[ks]];
        bfr[i] = *(const bf16x8*)&Bs[brow[i] + foff[ks]];
      }
      __builtin_amdgcn_s_setprio(1);
      #pragma unroll
      for (int mi = 0; mi < 4; ++mi)
        #pragma unroll
        for (int ni = 0; ni < 4; ++ni)
          acc[mi][ni] = __builtin_amdgcn_mfma_f32_16x16x32_bf16(
              af[mi], bfr[ni], acc[mi][ni], 0, 0, 0);
      __builtin_amdgcn_s_setprio(0);
    }

    __syncthreads();   // all reads of tile t done; staging-load drain is
                       // covered by the compute above (T14 placement)

    // ---- at s-tile end: epilogue + scan BEFORE overwriting As/Bs (Cs overlay)
    if (kt == 7) {
      const int sb = wm + q * 4;
      #pragma unroll
      for (int mi = 0; mi < 4; ++mi) {
        #pragma unroll
        for (int ni = 0; ni < 4; ++ni) {
          ushort4 o;
          o.x = f2bf(acc[mi][ni][0]); o.y = f2bf(acc[mi][ni][1]);
          o.z = f2bf(acc[mi][ni][2]); o.w = f2bf(acc[mi][ni][3]);
          *(ushort4*)&Cs[(wn + ni * 16 + ml) * 132 + sb + mi * 16] = o;
        }
      }
      __syncthreads();                // Cs visible
      if (tid < 128) {
        const ushort* col = &Cs[tid * 132];
        #pragma unroll
        for (int s0 = 0; s0 < 128; s0 += 16) {
          SCAN16(col, s0);
        }
      }
      __syncthreads();                // scan done before As/Bs rewrite
    }

    // ---- write staged regs -> LDS (tile t+1)
    if (t < 63) {
      #pragma unroll
      for (int jj = 0; jj < 4; ++jj) {
        *(uint4*)(lA + jj * 512) = rA[jj];   // 512 ushorts = 8 rows
        *(uint4*)(lB + jj * 512) = rB[jj];
      }
      __syncthreads();                // tile t+1 visible (~50cy exposed)
    }
  }

  // ---- h handoff (Cs/As free after final scan's sync)
  if (tid < 128) ((float*)smem)[tid] = fabsf(p);
  __syncthreads();

  // ---- Y[b, :] += h . Who[:, ht*128 .. +128)   (Who slice is L2-resident)
  {
    const float* hs = (const float*)smem;
    const float* w0 = Who + (size_t)tid * H_SZ + (size_t)ht * 128;
    const float* w1 = w0 + (size_t)256 * H_SZ;
    float y0 = 0.f, y1 = 0.f;
    #pragma unroll 8
    for (int k = 0; k < 128; k += 4) {
      float4 hv = *(const float4*)&hs[k];    // broadcast (same addr all lanes)
      float4 u0 = *(const float4*)&w0[k];
      float4 u1 = *(const float4*)&w1[k];
      y0 += hv.x * u0.x + hv.y * u0.y + hv.z * u0.z + hv.w * u0.w;
      y1 += hv.x * u1.x + hv.y * u1.y + hv.z * u1.z + hv.w * u1.w;
    }
    atomicAdd(&Y[(size_t)b * O_SZ + tid], y0);
    atomicAdd(&Y[(size_t)b * O_SZ + 256 + tid], y1);
  }
}

// ---------------------------------------------------------------- launch
extern "C" void kernel_launch(void* const* d_in, const int* in_sizes, int n_in,
                              void* d_out, int out_size, void* d_ws, size_t ws_size,
                              hipStream_t stream) {
  (void)in_sizes; (void)n_in; (void)out_size; (void)ws_size;
  const float* X   = (const float*)d_in[0];   // [1024][64][512]
  const float* Wih = (const float*)d_in[1];   // [2048][512]
  const float* hh  = (const float*)d_in[2];   // [2048]
  const float* Who = (const float*)d_in[3];   // [512][2048]
  const float* bho = (const float*)d_in[4];   // [512]
  float* Y = (float*)d_out;                   // [64][512]

  const size_t WBF = (size_t)H_SZ * I_SZ * 2;          // 2 MiB
  char* w = (char*)d_ws;
  ushort* Wbf = (ushort*)w;                            // 2 MiB
  ushort* Xbf = (ushort*)(w + WBF);                    // 64 MiB, [b][s][i]

  // W convert (tiny)
  {
    int n4w = (int)((size_t)H_SZ * I_SZ / 4);          // 262144
    convert_f32_bf16_kernel<<<n4w / 256, 256, 0, stream>>>(
        (const float4*)Wih, (ushort4*)Wbf, n4w);
  }

  // X convert + transpose to batch-major bf16
  convert_x_kernel<<<(S_LEN * B_SZ) / 4, 256, 0, stream>>>(X, Xbf);

  // Y <- bias (must complete before fused kernel's atomics; stream-ordered)
  init_y_kernel<<<(B_SZ * O_SZ) / 256, 256, 0, stream>>>(bho, Y);

  // fused GEMM + scan + projection
  fused_gemm_scan_kernel<<<1024, 256, 0, stream>>>(Xbf, Wbf, hh, Who, Y);
}

// Round 6
// 476.816 us; speedup vs baseline: 1.6395x; 1.6395x over previous
//
#include <hip/hip_runtime.h>
#include <hip/hip_bf16.h>
#include <stdint.h>

// Problem constants
#define S_LEN 1024
#define B_SZ  64
#define I_SZ  512
#define H_SZ  2048
#define O_SZ  512

typedef __bf16  bf16x8 __attribute__((ext_vector_type(8)));
typedef float   f32x4  __attribute__((ext_vector_type(4)));

static __device__ __forceinline__ ushort f2bf(float f) {
  union { float f; unsigned u; } v; v.f = f;
  unsigned r = v.u + 0x7FFFu + ((v.u >> 16) & 1u);   // RNE
  return (ushort)(r >> 16);
}
static __device__ __forceinline__ float bf2f(ushort u) {
  return __builtin_bit_cast(float, (unsigned)u << 16);
}

// async global->LDS, 16B per lane: LDS dest is WAVE-UNIFORM base + lane*16
#define GLOAD_LDS16(gp, lp) \
  __builtin_amdgcn_global_load_lds( \
      (__attribute__((address_space(1))) void*)(gp), \
      (__attribute__((address_space(3))) void*)(lp), 16, 0, 0)

// ---------------------------------------------------------------- W convert (tiny)
__global__ __launch_bounds__(256) void convert_f32_bf16_kernel(
    const float4* __restrict__ in, ushort4* __restrict__ out, int n4) {
  int i = blockIdx.x * 256 + threadIdx.x;
  if (i >= n4) return;
  float4 v = in[i];
  ushort4 o; o.x = f2bf(v.x); o.y = f2bf(v.y); o.z = f2bf(v.z); o.w = f2bf(v.w);
  out[i] = o;
}

// ---------------------------------------------------------------- X convert+transpose
// X[s][b][i] fp32 -> Xbf[b][s][i] bf16. One wave per (s,b) row.
__global__ __launch_bounds__(256) void convert_x_kernel(
    const float* __restrict__ X, ushort* __restrict__ Xt) {
  const int row  = blockIdx.x * 4 + (threadIdx.x >> 6);  // s*64 + b
  const int lane = threadIdx.x & 63;
  const int s = row >> 6, b = row & 63;
  const float* src = X + (size_t)row * I_SZ + lane * 8;
  float4 v0 = *(const float4*)src;
  float4 v1 = *(const float4*)(src + 4);
  union { ushort h[8]; uint4 v; } o;
  o.h[0] = f2bf(v0.x); o.h[1] = f2bf(v0.y); o.h[2] = f2bf(v0.z); o.h[3] = f2bf(v0.w);
  o.h[4] = f2bf(v1.x); o.h[5] = f2bf(v1.y); o.h[6] = f2bf(v1.z); o.h[7] = f2bf(v1.w);
  *(uint4*)(Xt + ((size_t)b * S_LEN + s) * I_SZ + lane * 8) = o.v;
}

// ---------------------------------------------------------------- Y = bias (runs BEFORE fused)
__global__ __launch_bounds__(256) void init_y_kernel(
    const float* __restrict__ bho, float* __restrict__ Y) {
  int idx = blockIdx.x * 256 + threadIdx.x;   // 0..32767
  Y[idx] = bho[idx & (O_SZ - 1)];
}

#define SCAN16(colp, s0_) do { \
    ushort4 v0 = *(const ushort4*)&(colp)[(s0_)]; \
    ushort4 v1 = *(const ushort4*)&(colp)[(s0_) + 4]; \
    ushort4 v2 = *(const ushort4*)&(colp)[(s0_) + 8]; \
    ushort4 v3 = *(const ushort4*)&(colp)[(s0_) + 12]; \
    p = fmaf(c, fabsf(p), bf2f(v0.x)); p = fmaf(c, fabsf(p), bf2f(v0.y)); \
    p = fmaf(c, fabsf(p), bf2f(v0.z)); p = fmaf(c, fabsf(p), bf2f(v0.w)); \
    p = fmaf(c, fabsf(p), bf2f(v1.x)); p = fmaf(c, fabsf(p), bf2f(v1.y)); \
    p = fmaf(c, fabsf(p), bf2f(v1.z)); p = fmaf(c, fabsf(p), bf2f(v1.w)); \
    p = fmaf(c, fabsf(p), bf2f(v2.x)); p = fmaf(c, fabsf(p), bf2f(v2.y)); \
    p = fmaf(c, fabsf(p), bf2f(v2.z)); p = fmaf(c, fabsf(p), bf2f(v2.w)); \
    p = fmaf(c, fabsf(p), bf2f(v3.x)); p = fmaf(c, fabsf(p), bf2f(v3.y)); \
    p = fmaf(c, fabsf(p), bf2f(v3.z)); p = fmaf(c, fabsf(p), bf2f(v3.w)); \
  } while (0)

// stage K-step T (BK=32 tile) into LDS buffers dA/dB via global_load_lds.
// Per lane: 2 A-loads + 2 B-loads. LDS dest base is wave-uniform (stOff);
// HW adds lane*16. Image: slot (lane&3) of row r0 + jj*16 + (lane>>2) holds
// global chunk ((lane&3) - (lane>>2))&3  (rotate swizzle, mod-4).
#define STAGE(dA, dB, T) do { \
    const ushort* ga_ = gA + (size_t)((T) >> 4) * (128 * I_SZ) + ((T) & 15) * 32; \
    const ushort* gb_ = gB + ((T) & 15) * 32; \
    GLOAD_LDS16(ga_,              (dA) + stOff); \
    GLOAD_LDS16(ga_ + 16 * I_SZ,  (dA) + stOff + 512); \
    GLOAD_LDS16(gb_,              (dB) + stOff); \
    GLOAD_LDS16(gb_ + 16 * I_SZ,  (dB) + stOff + 512); \
  } while (0)

// ---------------------------------------------------------------- fused GEMM + scan + projection
// Grid: 1024 blocks = (b, ht). DOUBLE-BUFFERED K-loop (BK=32, 128 steps), ONE
// barrier per step, T3 minimum-2-phase placement:
//   t: STAGE(t+1 -> nxt)  [issue-early]
//      8 ds_read_b128 + 16 MFMA from cur   [covers the staging latency]
//      __syncthreads()   [vmcnt(0) drain lands AFTER compute cover]
//      swap(cur, nxt)
// This removes the R0/R3 invariant limiter (sync immediately after staging
// issue, exposing full load latency 64x/block). The staging pipeline also no
// longer restarts at s-tile boundaries. Cs is separate (stride 130 ->
// conflict-free scan columns); the serial scan runs after the barrier in
// waves 0-1 only, overlapped with waves 2-3's next step.
// LDS = 2x(8KB A + 8KB B) + 33280B Cs = 66048 B -> 2 blocks/CU.
__global__ __launch_bounds__(256) void fused_gemm_scan_kernel(
    const ushort* __restrict__ Xbf,   // [64][1024][512] bf16, batch-major
    const ushort* __restrict__ Wbf,   // [2048][512] bf16
    const float* __restrict__ hh,     // [2048]
    const float* __restrict__ Who,    // [512][2048] fp32
    float* __restrict__ Y) {          // [64][512], pre-seeded with bias
  __shared__ __align__(16) ushort smem[33024];   // 66048 B
  // buf0: A @0, B @4096 ; buf1: A @8192, B @12288 ; Cs @16384 [128][130]
  ushort* Cs = smem + 16384;

  const int tid  = threadIdx.x;
  const int wave = tid >> 6;
  const int lane = tid & 63;

  const int bid = blockIdx.x;
  const int xcd = bid & 7;            // XCD (bid%8 heuristic)
  const int g   = bid >> 3;           // 0..127
  const int b   = (xcd << 3) | (g & 7);  // same-b -> same XCD (Xbf L2 reuse)
  const int ht  = g >> 3;             // h-tile 0..15

  const int wm = (wave >> 1) * 64;    // s-offset within tile
  const int wn = (wave & 1) * 64;     // h-offset within tile
  const int ml = lane & 15;
  const int q  = lane >> 4;

  // ---- staging geometry (BK=32): wave stages 32 rows x 32 ushorts per tile
  const int r0     = wave * 32;
  const int lrow   = lane >> 2;                  // 0..15
  const int lchunk = ((lane & 3) - lrow) & 3;    // rotate: slot holds chunk (slot-row)&3
  const ushort* gA = Xbf + (size_t)b * (S_LEN * I_SZ)
                   + (size_t)(r0 + lrow) * I_SZ + lchunk * 8;
  const ushort* gB = Wbf + (size_t)(ht * 128 + r0 + lrow) * I_SZ + lchunk * 8;
  const int stOff = r0 * 32;          // ushort offset of wave's staging region

  // ---- fragment read offsets: chunk q of row r lives at slot (q + r)&3
  const int foff = ((q + ml) & 3) * 8;
  int arow[4], brow[4];
  #pragma unroll
  for (int i = 0; i < 4; ++i) {
    arow[i] = (wm + i * 16 + ml) * 32;
    brow[i] = (wn + i * 16 + ml) * 32;
  }

  float c = 0.0f, p = 0.0f;           // scan state (p: pre-abs h)
  if (tid < 128) c = hh[ht * 128 + tid];

  ushort* curA = smem;          ushort* curB = smem + 4096;
  ushort* nxtA = smem + 8192;   ushort* nxtB = smem + 12288;

  // ---------------- prologue: stage step 0 (one exposed drain)
  STAGE(curA, curB, 0);
  __syncthreads();

  f32x4 acc[4][4];

  #pragma unroll 1
  for (int t = 0; t < 128; ++t) {     // t = st*16 + kt (BK=32)
    if ((t & 15) == 0) {
      #pragma unroll
      for (int mi = 0; mi < 4; ++mi)
        #pragma unroll
        for (int ni = 0; ni < 4; ++ni) {
          f32x4 z = {0.f, 0.f, 0.f, 0.f};
          acc[mi][ni] = z;
        }
    }

    // ---- issue next-step staging (flies under this step's compute)
    if (t < 127) STAGE(nxtA, nxtB, t + 1);

    // ---- compute step t from cur (compiler-scheduled ds_read/MFMA)
    {
      bf16x8 af[4], bfr[4];
      #pragma unroll
      for (int i = 0; i < 4; ++i) {
        af[i]  = *(const bf16x8*)&curA[arow[i] + foff];
        bfr[i] = *(const bf16x8*)&curB[brow[i] + foff];
      }
      __builtin_amdgcn_s_setprio(1);
      #pragma unroll
      for (int mi = 0; mi < 4; ++mi)
        #pragma unroll
        for (int ni = 0; ni < 4; ++ni)
          acc[mi][ni] = __builtin_amdgcn_mfma_f32_16x16x32_bf16(
              af[mi], bfr[ni], acc[mi][ni], 0, 0, 0);
      __builtin_amdgcn_s_setprio(0);
    }

    // ---- s-tile end: epilogue acc -> transposed Cs[h][s] (pre-barrier)
    if ((t & 15) == 15) {
      const int sb = wm + q * 4;
      #pragma unroll
      for (int mi = 0; mi < 4; ++mi) {
        #pragma unroll
        for (int ni = 0; ni < 4; ++ni) {
          ushort4 o;
          o.x = f2bf(acc[mi][ni][0]); o.y = f2bf(acc[mi][ni][1]);
          o.z = f2bf(acc[mi][ni][2]); o.w = f2bf(acc[mi][ni][3]);
          *(ushort4*)&Cs[(wn + ni * 16 + ml) * 130 + sb + mi * 16] = o;
        }
      }
    }

    __syncthreads();   // staged t+1 visible; reads of cur done; Cs visible

    // ---- scan (waves 0-1 only; overlaps waves 2-3's next step). Next
    //      epilogue is 16 barriers away -> no race on Cs.
    if ((t & 15) == 15 && tid < 128) {
      const ushort* col = &Cs[tid * 130];
      #pragma unroll
      for (int s0 = 0; s0 < 128; s0 += 16) {
        SCAN16(col, s0);
      }
    }

    // ---- swap buffers (named pointers, static per iteration)
    ushort* tA = curA; curA = nxtA; nxtA = tA;
    ushort* tB = curB; curB = nxtB; nxtB = tB;
  }

  // ---- h handoff (As0 region free; only tid<128 writes, then barrier)
  if (tid < 128) ((float*)smem)[tid] = fabsf(p);
  __syncthreads();

  // ---- Y[b, :] += h . Who[:, ht*128 .. +128)   (Who slice is L2-resident)
  {
    const float* hs = (const float*)smem;
    const float* w0 = Who + (size_t)tid * H_SZ + (size_t)ht * 128;
    const float* w1 = w0 + (size_t)256 * H_SZ;
    float y0 = 0.f, y1 = 0.f;
    #pragma unroll 8
    for (int k = 0; k < 128; k += 4) {
      float4 hv = *(const float4*)&hs[k];    // broadcast (same addr all lanes)
      float4 u0 = *(const float4*)&w0[k];
      float4 u1 = *(const float4*)&w1[k];
      y0 += hv.x * u0.x + hv.y * u0.y + hv.z * u0.z + hv.w * u0.w;
      y1 += hv.x * u1.x + hv.y * u1.y + hv.z * u1.z + hv.w * u1.w;
    }
    atomicAdd(&Y[(size_t)b * O_SZ + tid], y0);
    atomicAdd(&Y[(size_t)b * O_SZ + 256 + tid], y1);
  }
}

// ---------------------------------------------------------------- launch
extern "C" void kernel_launch(void* const* d_in, const int* in_sizes, int n_in,
                              void* d_out, int out_size, void* d_ws, size_t ws_size,
                              hipStream_t stream) {
  (void)in_sizes; (void)n_in; (void)out_size; (void)ws_size;
  const float* X   = (const float*)d_in[0];   // [1024][64][512]
  const float* Wih = (const float*)d_in[1];   // [2048][512]
  const float* hh  = (const float*)d_in[2];   // [2048]
  const float* Who = (const float*)d_in[3];   // [512][2048]
  const float* bho = (const float*)d_in[4];   // [512]
  float* Y = (float*)d_out;                   // [64][512]

  const size_t WBF = (size_t)H_SZ * I_SZ * 2;          // 2 MiB
  char* w = (char*)d_ws;
  ushort* Wbf = (ushort*)w;                            // 2 MiB
  ushort* Xbf = (ushort*)(w + WBF);                    // 64 MiB, [b][s][i]

  // W convert (tiny)
  {
    int n4w = (int)((size_t)H_SZ * I_SZ / 4);          // 262144
    convert_f32_bf16_kernel<<<n4w / 256, 256, 0, stream>>>(
        (const float4*)Wih, (ushort4*)Wbf, n4w);
  }

  // X convert + transpose to batch-major bf16
  convert_x_kernel<<<(S_LEN * B_SZ) / 4, 256, 0, stream>>>(X, Xbf);

  // Y <- bias (must complete before fused kernel's atomics; stream-ordered)
  init_y_kernel<<<(B_SZ * O_SZ) / 256, 256, 0, stream>>>(bho, Y);

  // fused GEMM + scan + projection
  fused_gemm_scan_kernel<<<1024, 256, 0, stream>>>(Xbf, Wbf, hh, Who, Y);
}

// Round 8
// 474.446 us; speedup vs baseline: 1.6477x; 1.0050x over previous
//
#include <hip/hip_runtime.h>
#include <hip/hip_bf16.h>
#include <stdint.h>

// Problem constants
#define S_LEN 1024
#define B_SZ  64
#define I_SZ  512
#define H_SZ  2048
#define O_SZ  512

typedef __bf16  bf16x8 __attribute__((ext_vector_type(8)));
typedef float   f32x4  __attribute__((ext_vector_type(4)));

static __device__ __forceinline__ ushort f2bf(float f) {
  union { float f; unsigned u; } v; v.f = f;
  unsigned r = v.u + 0x7FFFu + ((v.u >> 16) & 1u);   // RNE
  return (ushort)(r >> 16);
}
static __device__ __forceinline__ float bf2f(ushort u) {
  return __builtin_bit_cast(float, (unsigned)u << 16);
}

// async global->LDS, 16B per lane: LDS dest is WAVE-UNIFORM base + lane*16
#define GLOAD_LDS16(gp, lp) \
  __builtin_amdgcn_global_load_lds( \
      (__attribute__((address_space(1))) void*)(gp), \
      (__attribute__((address_space(3))) void*)(lp), 16, 0, 0)

// ---------------------------------------------------------------- W convert (tiny)
__global__ __launch_bounds__(256) void convert_f32_bf16_kernel(
    const float4* __restrict__ in, ushort4* __restrict__ out, int n4) {
  int i = blockIdx.x * 256 + threadIdx.x;
  if (i >= n4) return;
  float4 v = in[i];
  ushort4 o; o.x = f2bf(v.x); o.y = f2bf(v.y); o.z = f2bf(v.z); o.w = f2bf(v.w);
  out[i] = o;
}

// ---------------------------------------------------------------- X convert+transpose
// X[s][b][i] fp32 -> Xbf[b][s][i] bf16. One wave per (s,b) row.
__global__ __launch_bounds__(256) void convert_x_kernel(
    const float* __restrict__ X, ushort* __restrict__ Xt) {
  const int row  = blockIdx.x * 4 + (threadIdx.x >> 6);  // s*64 + b
  const int lane = threadIdx.x & 63;
  const int s = row >> 6, b = row & 63;
  const float* src = X + (size_t)row * I_SZ + lane * 8;
  float4 v0 = *(const float4*)src;
  float4 v1 = *(const float4*)(src + 4);
  union { ushort h[8]; uint4 v; } o;
  o.h[0] = f2bf(v0.x); o.h[1] = f2bf(v0.y); o.h[2] = f2bf(v0.z); o.h[3] = f2bf(v0.w);
  o.h[4] = f2bf(v1.x); o.h[5] = f2bf(v1.y); o.h[6] = f2bf(v1.z); o.h[7] = f2bf(v1.w);
  *(uint4*)(Xt + ((size_t)b * S_LEN + s) * I_SZ + lane * 8) = o.v;
}

// ---------------------------------------------------------------- Y = bias (runs BEFORE fused)
__global__ __launch_bounds__(256) void init_y_kernel(
    const float* __restrict__ bho, float* __restrict__ Y) {
  int idx = blockIdx.x * 256 + threadIdx.x;   // 0..32767
  Y[idx] = bho[idx & (O_SZ - 1)];
}

#define SCAN16(colp, s0_) do { \
    ushort4 v0 = *(const ushort4*)&(colp)[(s0_)]; \
    ushort4 v1 = *(const ushort4*)&(colp)[(s0_) + 4]; \
    ushort4 v2 = *(const ushort4*)&(colp)[(s0_) + 8]; \
    ushort4 v3 = *(const ushort4*)&(colp)[(s0_) + 12]; \
    p = fmaf(c, fabsf(p), bf2f(v0.x)); p = fmaf(c, fabsf(p), bf2f(v0.y)); \
    p = fmaf(c, fabsf(p), bf2f(v0.z)); p = fmaf(c, fabsf(p), bf2f(v0.w)); \
    p = fmaf(c, fabsf(p), bf2f(v1.x)); p = fmaf(c, fabsf(p), bf2f(v1.y)); \
    p = fmaf(c, fabsf(p), bf2f(v1.z)); p = fmaf(c, fabsf(p), bf2f(v1.w)); \
    p = fmaf(c, fabsf(p), bf2f(v2.x)); p = fmaf(c, fabsf(p), bf2f(v2.y)); \
    p = fmaf(c, fabsf(p), bf2f(v2.z)); p = fmaf(c, fabsf(p), bf2f(v2.w)); \
    p = fmaf(c, fabsf(p), bf2f(v3.x)); p = fmaf(c, fabsf(p), bf2f(v3.y)); \
    p = fmaf(c, fabsf(p), bf2f(v3.z)); p = fmaf(c, fabsf(p), bf2f(v3.w)); \
  } while (0)

// stage K-step T (BK=32) into LDS buffers dA/dB via global_load_lds.
// Per wave: 2 A-gloads + 2 B-gloads (each: 16 rows x 64B, lanes linear).
// Storage image: slot s of row r holds chunk c = (s - (r>>1)) & 3 -- this
// makes each quarter-wave's 16 fragment reads spread over 32 banks at
// <=2 lanes/bank (conflict-free), unlike R6's (s - r)&3 which was 4-way.
// Lane map: lane l covers row r0 + g*16 + (l>>2), slot l&3, global chunk
// ((l&3) - (l>>3)) & 3  (the (r>>1) term: r0, g*16 vanish mod 4).
#define STAGE(dA, dB, T) do { \
    const ushort* ga_ = gA + (size_t)((T) >> 4) * (128 * I_SZ) + ((T) & 15) * 32; \
    const ushort* gb_ = gB + ((T) & 15) * 32; \
    GLOAD_LDS16(ga_,              (dA) + stOff); \
    GLOAD_LDS16(ga_ + 16 * I_SZ,  (dA) + stOff + 512); \
    GLOAD_LDS16(gb_,              (dB) + stOff); \
    GLOAD_LDS16(gb_ + 16 * I_SZ,  (dB) + stOff + 512); \
  } while (0)

// ---------------------------------------------------------------- fused GEMM + scan + projection
// Grid: 1024 blocks = (b, ht). Double-buffered BK=32 K-loop (128 steps), ONE
// barrier per step with T3 placement (stage issue-early, drain after compute):
//   t: STAGE(t+1 -> nxt); 8 ds_read_b128 + 16 MFMA from cur; __syncthreads().
// R6's defects fixed: (1) conflict-free sigma rotate (see STAGE comment);
// (2) Cs halved to a 64-s half-tile -> LDS 49664 B -> 3 blocks/CU (was 2),
// giving +50% co-resident waves to absorb latency/barrier stalls cross-block.
// s-tile epilogue in 2 phases: waves 0-1 (s 0..63) write+scan, then waves
// 2-3 (s 64..127) write, scan overlapping waves 2-3's next K-step.
__global__ __launch_bounds__(256) void fused_gemm_scan_kernel(
    const ushort* __restrict__ Xbf,   // [64][1024][512] bf16, batch-major
    const ushort* __restrict__ Wbf,   // [2048][512] bf16
    const float* __restrict__ hh,     // [2048]
    const float* __restrict__ Who,    // [512][2048] fp32
    float* __restrict__ Y) {          // [64][512], pre-seeded with bias
  __shared__ __align__(16) ushort smem[24832];   // 49664 B -> 3 blocks/CU
  // buf0: A @0, B @4096 ; buf1: A @8192, B @12288 ; Cs @16384 [128][66]
  ushort* Cs = smem + 16384;

  const int tid  = threadIdx.x;
  const int wave = tid >> 6;
  const int lane = tid & 63;

  const int bid = blockIdx.x;
  const int xcd = bid & 7;            // XCD (bid%8 heuristic)
  const int g   = bid >> 3;           // 0..127
  const int b   = (xcd << 3) | (g & 7);  // same-b -> same XCD (Xbf L2 reuse)
  const int ht  = g >> 3;             // h-tile 0..15

  const int wm = (wave >> 1) * 64;    // s-offset within tile
  const int wn = (wave & 1) * 64;     // h-offset within tile
  const int ml = lane & 15;
  const int q  = lane >> 4;

  // ---- staging geometry (BK=32): wave stages 32 rows x 32 ushorts per tile
  const int r0     = wave * 32;
  const int lrow   = lane >> 2;                        // 0..15
  const int lchunk = ((lane & 3) - (lane >> 3)) & 3;   // sigma rotate source
  const ushort* gA = Xbf + (size_t)b * (S_LEN * I_SZ)
                   + (size_t)(r0 + lrow) * I_SZ + lchunk * 8;
  const ushort* gB = Wbf + (size_t)(ht * 128 + r0 + lrow) * I_SZ + lchunk * 8;
  const int stOff = r0 * 32;          // ushort offset of wave's staging region

  // ---- fragment reads: chunk q of row r lives at slot (q + (r>>1)) & 3;
  //      r = wm + i*16 + ml -> (r>>1) === (ml>>1) mod 4 (wm>>1, i*8 vanish)
  const int foff = ((q + (ml >> 1)) & 3) * 8;
  int arow[4], brow[4];
  #pragma unroll
  for (int i = 0; i < 4; ++i) {
    arow[i] = (wm + i * 16 + ml) * 32;
    brow[i] = (wn + i * 16 + ml) * 32;
  }

  float c = 0.0f, p = 0.0f;           // scan state (p: pre-abs h)
  if (tid < 128) c = hh[ht * 128 + tid];

  ushort* curA = smem;          ushort* curB = smem + 4096;
  ushort* nxtA = smem + 8192;   ushort* nxtB = smem + 12288;

  // ---------------- prologue: stage step 0 (one exposed drain)
  STAGE(curA, curB, 0);
  __syncthreads();

  f32x4 acc[4][4];

  #pragma unroll 1
  for (int t = 0; t < 128; ++t) {     // t = st*16 + kt (BK=32)
    if ((t & 15) == 0) {
      #pragma unroll
      for (int mi = 0; mi < 4; ++mi)
        #pragma unroll
        for (int ni = 0; ni < 4; ++ni) {
          f32x4 z = {0.f, 0.f, 0.f, 0.f};
          acc[mi][ni] = z;
        }
    }

    // ---- issue next-step staging (flies under this step's compute)
    if (t < 127) STAGE(nxtA, nxtB, t + 1);

    // ---- compute step t from cur (compiler-scheduled ds_read/MFMA)
    {
      bf16x8 af[4], bfr[4];
      #pragma unroll
      for (int i = 0; i < 4; ++i) {
        af[i]  = *(const bf16x8*)&curA[arow[i] + foff];
        bfr[i] = *(const bf16x8*)&curB[brow[i] + foff];
      }
      __builtin_amdgcn_s_setprio(1);
      #pragma unroll
      for (int mi = 0; mi < 4; ++mi)
        #pragma unroll
        for (int ni = 0; ni < 4; ++ni)
          acc[mi][ni] = __builtin_amdgcn_mfma_f32_16x16x32_bf16(
              af[mi], bfr[ni], acc[mi][ni], 0, 0, 0);
      __builtin_amdgcn_s_setprio(0);
    }

    __syncthreads();   // staged t+1 visible; all reads of cur done;
                       // vmcnt(0) drain covered by the compute above

    // ---- s-tile end: two-phase epilogue + scan on the half-size Cs
    if ((t & 15) == 15) {
      // phase 1: waves 0-1 (wm=0) write s 0..63
      if (wave < 2) {
        #pragma unroll
        for (int mi = 0; mi < 4; ++mi)
          #pragma unroll
          for (int ni = 0; ni < 4; ++ni) {
            ushort4 o;
            o.x = f2bf(acc[mi][ni][0]); o.y = f2bf(acc[mi][ni][1]);
            o.z = f2bf(acc[mi][ni][2]); o.w = f2bf(acc[mi][ni][3]);
            *(ushort4*)&Cs[(wn + ni * 16 + ml) * 66 + mi * 16 + q * 4] = o;
          }
      }
      __syncthreads();
      if (tid < 128) {                 // scan s 0..63
        const ushort* col = &Cs[tid * 66];
        SCAN16(col, 0); SCAN16(col, 16); SCAN16(col, 32); SCAN16(col, 48);
      }
      __syncthreads();                 // scan reads done before phase-2 write
      // phase 2: waves 2-3 (wm=64) write s 64..127
      if (wave >= 2) {
        #pragma unroll
        for (int mi = 0; mi < 4; ++mi)
          #pragma unroll
          for (int ni = 0; ni < 4; ++ni) {
            ushort4 o;
            o.x = f2bf(acc[mi][ni][0]); o.y = f2bf(acc[mi][ni][1]);
            o.z = f2bf(acc[mi][ni][2]); o.w = f2bf(acc[mi][ni][3]);
            *(ushort4*)&Cs[(wn + ni * 16 + ml) * 66 + mi * 16 + q * 4] = o;
          }
      }
      __syncthreads();
      if (tid < 128) {                 // scan s 64..127 (overlaps waves 2-3's
        const ushort* col = &Cs[tid * 66];   // next K-step; rejoined at its barrier)
        SCAN16(col, 0); SCAN16(col, 16); SCAN16(col, 32); SCAN16(col, 48);
      }
      // no barrier: next epilogue is 16 step-barriers away, and waves 0-1
      // can't pass the next step barrier before finishing the scan.
    }

    // ---- swap buffers
    ushort* tA = curA; curA = nxtA; nxtA = tA;
    ushort* tB = curB; curB = nxtB; nxtB = tB;
  }

  // ---- h handoff (buffers idle; Cs consumed)
  if (tid < 128) ((float*)smem)[tid] = fabsf(p);
  __syncthreads();

  // ---- Y[b, :] += h . Who[:, ht*128 .. +128)   (Who slice is L2-resident)
  {
    const float* hs = (const float*)smem;
    const float* w0 = Who + (size_t)tid * H_SZ + (size_t)ht * 128;
    const float* w1 = w0 + (size_t)256 * H_SZ;
    float y0 = 0.f, y1 = 0.f;
    #pragma unroll 8
    for (int k = 0; k < 128; k += 4) {
      float4 hv = *(const float4*)&hs[k];    // broadcast (same addr all lanes)
      float4 u0 = *(const float4*)&w0[k];
      float4 u1 = *(const float4*)&w1[k];
      y0 += hv.x * u0.x + hv.y * u0.y + hv.z * u0.z + hv.w * u0.w;
      y1 += hv.x * u1.x + hv.y * u1.y + hv.z * u1.z + hv.w * u1.w;
    }
    atomicAdd(&Y[(size_t)b * O_SZ + tid], y0);
    atomicAdd(&Y[(size_t)b * O_SZ + 256 + tid], y1);
  }
}

// ---------------------------------------------------------------- launch
extern "C" void kernel_launch(void* const* d_in, const int* in_sizes, int n_in,
                              void* d_out, int out_size, void* d_ws, size_t ws_size,
                              hipStream_t stream) {
  (void)in_sizes; (void)n_in; (void)out_size; (void)ws_size;
  const float* X   = (const float*)d_in[0];   // [1024][64][512]
  const float* Wih = (const float*)d_in[1];   // [2048][512]
  const float* hh  = (const float*)d_in[2];   // [2048]
  const float* Who = (const float*)d_in[3];   // [512][2048]
  const float* bho = (const float*)d_in[4];   // [512]
  float* Y = (float*)d_out;                   // [64][512]

  const size_t WBF = (size_t)H_SZ * I_SZ * 2;          // 2 MiB
  char* w = (char*)d_ws;
  ushort* Wbf = (ushort*)w;                            // 2 MiB
  ushort* Xbf = (ushort*)(w + WBF);                    // 64 MiB, [b][s][i]

  // W convert (tiny)
  {
    int n4w = (int)((size_t)H_SZ * I_SZ / 4);          // 262144
    convert_f32_bf16_kernel<<<n4w / 256, 256, 0, stream>>>(
        (const float4*)Wih, (ushort4*)Wbf, n4w);
  }

  // X convert + transpose to batch-major bf16
  convert_x_kernel<<<(S_LEN * B_SZ) / 4, 256, 0, stream>>>(X, Xbf);

  // Y <- bias (must complete before fused kernel's atomics; stream-ordered)
  init_y_kernel<<<(B_SZ * O_SZ) / 256, 256, 0, stream>>>(bho, Y);

  // fused GEMM + scan + projection
  fused_gemm_scan_kernel<<<1024, 256, 0, stream>>>(Xbf, Wbf, hh, Who, Y);
}